// Round 1
// baseline (1059.823 us; speedup 1.0000x reference)
//
#include <hip/hip_runtime.h>

#define D 64
#define SCAN_B 1024

__device__ __forceinline__ float sigmoidf_(float x) {
    return 1.0f / (1.0f + __expf(-x));
}

// ---------------- precompute kernels ----------------

__global__ __launch_bounds__(256) void count_deg(const int* __restrict__ dst,
                                                 int* __restrict__ cnt, int E) {
    int e = blockIdx.x * 256 + threadIdx.x;
    if (e < E) atomicAdd(&cnt[dst[e]], 1);
}

__global__ __launch_bounds__(256) void calc_dinv(const int* __restrict__ cnt,
                                                 float* __restrict__ dinv, int N) {
    int n = blockIdx.x * 256 + threadIdx.x;
    if (n < N) dinv[n] = rsqrtf((float)cnt[n] + 1.0f);
}

// exclusive scan, hierarchical: per-block scan + block sums
__global__ __launch_bounds__(SCAN_B) void scan_block(const int* __restrict__ cnt,
                                                     int* __restrict__ out,
                                                     int* __restrict__ bsum, int N) {
    __shared__ int tmp[SCAN_B];
    int t = threadIdx.x;
    int gbase = blockIdx.x * SCAN_B;
    int v = (gbase + t < N) ? cnt[gbase + t] : 0;
    tmp[t] = v;
    __syncthreads();
    for (int off = 1; off < SCAN_B; off <<= 1) {
        int x = (t >= off) ? tmp[t - off] : 0;
        __syncthreads();
        tmp[t] += x;
        __syncthreads();
    }
    int incl = tmp[t];
    if (gbase + t < N) out[gbase + t] = incl - v;  // exclusive
    if (t == SCAN_B - 1) bsum[blockIdx.x] = incl;
}

__global__ __launch_bounds__(256) void scan_add(int* __restrict__ ptr,
                                                const int* __restrict__ boff,
                                                int* __restrict__ cursor, int N, int E) {
    int i = blockIdx.x * 256 + threadIdx.x;
    if (i < N) {
        int v = ptr[i] + boff[i / SCAN_B];
        ptr[i] = v;
        cursor[i] = v;
    }
    if (i == 0) ptr[N] = E;
}

__global__ __launch_bounds__(256) void fill_csr(const int* __restrict__ src,
                                                const int* __restrict__ dst,
                                                int* __restrict__ cursor,
                                                int* __restrict__ sorted, int E) {
    int e = blockIdx.x * 256 + threadIdx.x;
    if (e < E) {
        int p = atomicAdd(&cursor[dst[e]], 1);
        sorted[p] = src[e];
    }
}

// ---------------- per-layer kernels ----------------

// g[n][c] = ((in[n][k] * A[k] + C[k]) @ W[k][c]) * dinv[n]      (A/C optional)
__global__ __launch_bounds__(256) void gemm_g(const float* __restrict__ in,
                                              const float* __restrict__ W,
                                              const float* __restrict__ Aaf,
                                              const float* __restrict__ Caf,
                                              const float* __restrict__ dinv,
                                              float* __restrict__ g, int N) {
    int n = blockIdx.x * 256 + threadIdx.x;
    if (n >= N) return;
    float row[D];
    const float4* in4 = reinterpret_cast<const float4*>(in) + (size_t)n * (D / 4);
#pragma unroll
    for (int kk = 0; kk < D / 4; kk++) {
        float4 v = in4[kk];
        row[4 * kk + 0] = v.x;
        row[4 * kk + 1] = v.y;
        row[4 * kk + 2] = v.z;
        row[4 * kk + 3] = v.w;
    }
    if (Aaf) {
#pragma unroll
        for (int k = 0; k < D; k++) row[k] = fmaf(row[k], Aaf[k], Caf[k]);
    }
    float dn = dinv[n];
    float4* g4 = reinterpret_cast<float4*>(g) + (size_t)n * (D / 4);
#pragma unroll
    for (int cg = 0; cg < 4; cg++) {
        float acc[16];
#pragma unroll
        for (int j = 0; j < 16; j++) acc[j] = 0.f;
#pragma unroll
        for (int k = 0; k < D; k++) {
            float r = row[k];
#pragma unroll
            for (int j = 0; j < 16; j++)
                acc[j] = fmaf(r, W[k * D + cg * 16 + j], acc[j]);
        }
#pragma unroll
        for (int j4 = 0; j4 < 4; j4++) {
            float4 o;
            o.x = acc[4 * j4 + 0] * dn;
            o.y = acc[4 * j4 + 1] * dn;
            o.z = acc[4 * j4 + 2] * dn;
            o.w = acc[4 * j4 + 3] * dn;
            g4[cg * 4 + j4] = o;
        }
    }
}

// act[n] = act_fn( dinv[n]*(g[n] + sum_{src in N(n)} g[src]) + b ), plus BN stats
__global__ __launch_bounds__(256) void agg_act(const float* __restrict__ g,
                                               const int* __restrict__ ptr,
                                               const int* __restrict__ srcs,
                                               const float* __restrict__ dinv,
                                               const float* __restrict__ bias,
                                               float* __restrict__ act,
                                               float* __restrict__ ssum,
                                               float* __restrict__ sssq,
                                               int mode, int N) {
    __shared__ float red[2][4][64];
    int lane = threadIdx.x & 63;
    int wv = threadIdx.x >> 6;
    float b = bias[lane];
    float psum = 0.f, pssq = 0.f;
    for (int n = blockIdx.x * 4 + wv; n < N; n += gridDim.x * 4) {
        float acc = g[(size_t)n * 64 + lane];
        int s = ptr[n], e = ptr[n + 1];
        int i = s;
        for (; i + 3 < e; i += 4) {
            int u0 = srcs[i], u1 = srcs[i + 1], u2 = srcs[i + 2], u3 = srcs[i + 3];
            float v0 = g[(size_t)u0 * 64 + lane];
            float v1 = g[(size_t)u1 * 64 + lane];
            float v2 = g[(size_t)u2 * 64 + lane];
            float v3 = g[(size_t)u3 * 64 + lane];
            acc += (v0 + v1) + (v2 + v3);
        }
        for (; i < e; i++) acc += g[(size_t)srcs[i] * 64 + lane];
        float o = fmaf(acc, dinv[n], b);
        float a;
        if (mode == 0)      a = sigmoidf_(o);
        else if (mode == 1) a = o;
        else                a = sigmoidf_(0.5f * o);
        act[(size_t)n * 64 + lane] = a;
        psum += a;
        pssq += a * a;
    }
    red[0][wv][lane] = psum;
    red[1][wv][lane] = pssq;
    __syncthreads();
    if (wv == 0) {
        float t0 = red[0][0][lane] + red[0][1][lane] + red[0][2][lane] + red[0][3][lane];
        float t1 = red[1][0][lane] + red[1][1][lane] + red[1][2][lane] + red[1][3][lane];
        atomicAdd(&ssum[lane], t0);
        atomicAdd(&sssq[lane], t1);
    }
}

// A[c] = rsqrt(var+eps)*gamma[c];  C[c] = beta[c] - mean*A[c]
__global__ __launch_bounds__(64) void finalize_aff(const float* __restrict__ ssum,
                                                   const float* __restrict__ sssq,
                                                   const float* __restrict__ gamma,
                                                   const float* __restrict__ beta,
                                                   float* __restrict__ A,
                                                   float* __restrict__ C, float invN) {
    int c = threadIdx.x;
    float m = ssum[c] * invN;
    float var = sssq[c] * invN - m * m;
    float rs = rsqrtf(var + 1e-4f);
    float a = rs * gamma[c];
    A[c] = a;
    C[c] = fmaf(-m, a, beta[c]);
}

__global__ __launch_bounds__(256) void bn_apply(const float* __restrict__ act,
                                                const float* __restrict__ A,
                                                const float* __restrict__ C,
                                                float* __restrict__ out, int total4) {
    int p = blockIdx.x * 256 + threadIdx.x;
    if (p < total4) {
        float4 v = reinterpret_cast<const float4*>(act)[p];
        int cb = (p & 15) * 4;
        float4 o;
        o.x = fmaf(v.x, A[cb + 0], C[cb + 0]);
        o.y = fmaf(v.y, A[cb + 1], C[cb + 1]);
        o.z = fmaf(v.z, A[cb + 2], C[cb + 2]);
        o.w = fmaf(v.w, A[cb + 3], C[cb + 3]);
        reinterpret_cast<float4*>(out)[p] = o;
    }
}

// ---------------- launch ----------------

extern "C" void kernel_launch(void* const* d_in, const int* in_sizes, int n_in,
                              void* d_out, int out_size, void* d_ws, size_t ws_size,
                              hipStream_t stream) {
    const int N = in_sizes[0] / D;
    const int E = in_sizes[1] / 2;

    const float* x = (const float*)d_in[0];
    const int* ei = (const int*)d_in[1];
    const int* src_in = ei;
    const int* dst_in = ei + E;
    const float* encW = (const float*)d_in[3];
    const float* encb = (const float*)d_in[4];
    const float* encg = (const float*)d_in[5];
    const float* encbe = (const float*)d_in[6];
    const float* attW = (const float*)d_in[7];
    const float* attb = (const float*)d_in[8];
    const float* attg = (const float*)d_in[9];
    const float* attbe = (const float*)d_in[10];
    const float* strW = (const float*)d_in[11];
    const float* strb = (const float*)d_in[12];
    const float* strg = (const float*)d_in[13];
    const float* strbe = (const float*)d_in[14];

    char* ws = (char*)d_ws;
    size_t off = 0;
    auto alloc = [&](size_t bytes) -> char* {
        char* p = ws + off;
        off += (bytes + 255) & ~(size_t)255;
        return p;
    };
    int* cnt = (int*)alloc((size_t)N * 4);
    int* csr = (int*)alloc((size_t)(N + 1) * 4);
    int* cursor = (int*)alloc((size_t)N * 4);
    int* sorted = (int*)alloc((size_t)E * 4);
    int* bsum = (int*)alloc(1024 * 4);
    int* boff = (int*)alloc(1024 * 4);
    int* dummy = (int*)alloc(1024 * 4);
    float* dinv = (float*)alloc((size_t)N * 4);
    float* stats = (float*)alloc(6 * 128 * 4);
    float* aff = (float*)alloc(6 * 128 * 4);
    float* gbuf = (float*)alloc((size_t)N * D * 4);
    float* abuf = (float*)alloc((size_t)N * D * 4);

    float* out_str = (float*)d_out;
    float* out_att = out_str + (size_t)N * D;
    float* out_enc = out_att + (size_t)N * D;

    hipMemsetAsync(cnt, 0, (size_t)N * 4, stream);
    hipMemsetAsync(stats, 0, 6 * 128 * 4, stream);

    int gE = (E + 255) / 256;
    int gN = (N + 255) / 256;
    int nsb = (N + SCAN_B - 1) / SCAN_B;
    int total4 = N * D / 4;
    int g4 = (total4 + 255) / 256;

    count_deg<<<gE, 256, 0, stream>>>(dst_in, cnt, E);
    calc_dinv<<<gN, 256, 0, stream>>>(cnt, dinv, N);
    scan_block<<<nsb, SCAN_B, 0, stream>>>(cnt, csr, bsum, N);
    scan_block<<<1, SCAN_B, 0, stream>>>(bsum, boff, dummy, nsb);
    scan_add<<<gN, 256, 0, stream>>>(csr, boff, cursor, N, E);
    fill_csr<<<gE, 256, 0, stream>>>(src_in, dst_in, cursor, sorted, E);

    auto layer = [&](const float* in, const float* W, const float* bias,
                     const float* gamma, const float* beta, int li, int prev_aff,
                     int mode) {
        const float* Aaf = (prev_aff >= 0) ? (aff + prev_aff * 128) : nullptr;
        const float* Caf = (prev_aff >= 0) ? (aff + prev_aff * 128 + 64) : nullptr;
        gemm_g<<<gN, 256, 0, stream>>>(in, W, Aaf, Caf, dinv, gbuf, N);
        agg_act<<<2048, 256, 0, stream>>>(gbuf, csr, sorted, dinv, bias, abuf,
                                          stats + li * 128, stats + li * 128 + 64,
                                          mode, N);
        finalize_aff<<<1, 64, 0, stream>>>(stats + li * 128, stats + li * 128 + 64,
                                           gamma, beta, aff + li * 128,
                                           aff + li * 128 + 64, 1.0f / (float)N);
    };

    // ---- encoder ----
    layer(x, encW, encb, encg, encbe, 0, -1, 0);
    layer(abuf, encW + 4096, encb + 64, encg + 64, encbe + 64, 1, 0, 0);
    bn_apply<<<g4, 256, 0, stream>>>(abuf, aff + 1 * 128, aff + 1 * 128 + 64,
                                     out_enc, total4);
    // ---- attribute decoder ----
    layer(out_enc, attW, attb, attg, attbe, 2, -1, 0);
    layer(abuf, attW + 4096, attb + 64, attg + 64, attbe + 64, 3, 2, 1);
    bn_apply<<<g4, 256, 0, stream>>>(abuf, aff + 3 * 128, aff + 3 * 128 + 64,
                                     out_att, total4);
    // ---- structure decoder ----
    layer(out_enc, strW, strb, strg, strbe, 4, -1, 0);
    layer(abuf, strW + 4096, strb + 64, strg + 64, strbe + 64, 5, 4, 2);
    bn_apply<<<g4, 256, 0, stream>>>(abuf, aff + 5 * 128, aff + 5 * 128 + 64,
                                     out_str, total4);
}